// Round 16
// baseline (392.002 us; speedup 1.0000x reference)
//
#include <hip/hip_runtime.h>
#include <math.h>

constexpr int B = 64, S = 128, V = 5000;
constexpr int DT = 300, DA = 74, DV = 35;
constexpr int H = 128, C16 = 16;
constexpr int Mdim = 4096, UNITS = 256;
constexpr int T_ = B * S;   // 8192 tokens
constexpr int NCH = 128;    // K-chunks of 32 complex (64 real) in Gm

typedef __attribute__((ext_vector_type(8))) short short8v;
typedef __attribute__((ext_vector_type(4))) float f32x4;
typedef _Float16 half2v __attribute__((ext_vector_type(2)));

__device__ __forceinline__ unsigned short f2bf(float x) {
    unsigned int u = __float_as_uint(x);
    unsigned int r = (u + 0x7fffu + ((u >> 16) & 1u)) >> 16;
    return (unsigned short)r;
}
__device__ __forceinline__ float bf2f(unsigned short h) {
    return __uint_as_float(((unsigned int)h) << 16);
}
__device__ __forceinline__ float fsig(float x) { return 1.f / (1.f + __expf(-x)); }
__device__ __forceinline__ float ftanh(float x) {
    float t = __expf(2.f * x);
    return (t - 1.f) / (t + 1.f);
}

union U2 { unsigned int u; half2v v; };

// ---------------------------------------------------------------------------
// k_embed: xW[token, j] = emb[idx[token]] @ Wih.T + bih + bhh   (8192 x 512)
// ---------------------------------------------------------------------------
__global__ __launch_bounds__(256, 2) void k_embed(const int* __restrict__ idx,
                                                  const float* __restrict__ emb,
                                                  const float* __restrict__ Wih,
                                                  const float* __restrict__ bih,
                                                  const float* __restrict__ bhh,
                                                  float* __restrict__ xW) {
    __shared__ float As[60][132];   // [kk][token]
    __shared__ float Ws[60][132];   // [kk][j]
    __shared__ int sidx[128];
    int tid = threadIdx.x;
    int t0 = (blockIdx.x >> 2) * 128;
    int j0 = (blockIdx.x & 3) * 128;
    if (tid < 128) sidx[tid] = idx[t0 + tid];

    int jq = tid & 15, tq = tid >> 4;
    float acc[8][8];
#pragma unroll
    for (int r = 0; r < 8; r++)
#pragma unroll
        for (int cc = 0; cc < 8; cc++) acc[r][cc] = 0.f;

    __syncthreads();
    for (int c = 0; c < 5; c++) {
        int k0 = c * 60;
        if (c) __syncthreads();
        for (int i = tid; i < 128 * 60; i += 256) {
            int tok = i / 60, kk = i - tok * 60;
            As[kk][tok] = emb[(size_t)sidx[tok] * 300 + k0 + kk];
            Ws[kk][tok] = Wih[(size_t)(j0 + tok) * 300 + k0 + kk];
        }
        __syncthreads();
#pragma unroll 4
        for (int kk = 0; kk < 60; kk++) {
            float4 a0 = *(const float4*)&As[kk][tq * 8];
            float4 a1 = *(const float4*)&As[kk][tq * 8 + 4];
            float4 w0 = *(const float4*)&Ws[kk][jq * 8];
            float4 w1 = *(const float4*)&Ws[kk][jq * 8 + 4];
            float a[8] = {a0.x, a0.y, a0.z, a0.w, a1.x, a1.y, a1.z, a1.w};
            float w[8] = {w0.x, w0.y, w0.z, w0.w, w1.x, w1.y, w1.z, w1.w};
#pragma unroll
            for (int r = 0; r < 8; r++)
#pragma unroll
                for (int cc = 0; cc < 8; cc++)
                    acc[r][cc] = fmaf(a[r], w[cc], acc[r][cc]);
        }
    }
    float bb[8];
#pragma unroll
    for (int cc = 0; cc < 8; cc++) {
        int j = j0 + jq * 8 + cc;
        bb[cc] = bih[j] + bhh[j];
    }
#pragma unroll
    for (int r = 0; r < 8; r++) {
        int t = t0 + tq * 8 + r;
        float4 o0, o1;
        o0.x = acc[r][0] + bb[0]; o0.y = acc[r][1] + bb[1];
        o0.z = acc[r][2] + bb[2]; o0.w = acc[r][3] + bb[3];
        o1.x = acc[r][4] + bb[4]; o1.y = acc[r][5] + bb[5];
        o1.z = acc[r][6] + bb[6]; o1.w = acc[r][7] + bb[7];
        *(float4*)&xW[(size_t)t * 512 + j0 + jq * 8] = o0;
        *(float4*)&xW[(size_t)t * 512 + j0 + jq * 8 + 4] = o1;
    }
}

// ---------------------------------------------------------------------------
// k_lstm v5 (round-15 winner): 256 threads, 2 gate-rows per thread.
// ---------------------------------------------------------------------------
__global__ __launch_bounds__(256) void k_lstm(const float* __restrict__ xW,
                                              const float* __restrict__ Whh,
                                              float* __restrict__ hs) {
    __shared__ __align__(16) unsigned int hsm[2][64];   // 128 fp16 channels, packed
    int b = blockIdx.x, tid = threadIdx.x;
    int ch = tid >> 1, gp = tid & 1;    // gp0: gates {0,1}=i,f ; gp1: {2,3}=g,o
    int g0 = gp * 2, g1 = gp * 2 + 1;

    unsigned int wA[64], wB[64];
    const float* wr0 = Whh + (size_t)(g0 * 128 + ch) * 128;
    const float* wr1 = Whh + (size_t)(g1 * 128 + ch) * 128;
#pragma unroll
    for (int k = 0; k < 64; k++) {
        U2 t;
        t.v[0] = (_Float16)wr0[2 * k];
        t.v[1] = (_Float16)wr0[2 * k + 1];
        wA[k] = t.u;
        U2 u;
        u.v[0] = (_Float16)wr1[2 * k];
        u.v[1] = (_Float16)wr1[2 * k + 1];
        wB[k] = u.u;
    }
    if (tid < 64) { hsm[0][tid] = 0u; hsm[1][tid] = 0u; }

    const float* xwb = xW + (size_t)b * S * 512;
    float* hb = hs + (size_t)b * S * H;
    int gch0 = g0 * 128 + ch, gch1 = g1 * 128 + ch;
    float xn0 = xwb[gch0], xn1 = xwb[gch1];
    float c = 0.f;
    __syncthreads();

    int cur = 0;
    for (int s = 0; s < S; s++) {
        float xc0 = xn0, xc1 = xn1;
        if (s + 1 < S) {
            xn0 = xwb[(size_t)(s + 1) * 512 + gch0];
            xn1 = xwb[(size_t)(s + 1) * 512 + gch1];
        }
        float a0 = 0.f, a1 = 0.f, a2 = 0.f, a3 = 0.f;
        float b0 = 0.f, b1 = 0.f, b2 = 0.f, b3 = 0.f;
#pragma unroll
        for (int kb = 0; kb < 16; kb++) {
            uint4 hv = *(const uint4*)&hsm[cur][kb * 4];
            U2 h0, h1, h2, h3;
            h0.u = hv.x; h1.u = hv.y; h2.u = hv.z; h3.u = hv.w;
            U2 xa0, xa1, xa2, xa3, xb0, xb1, xb2, xb3;
            xa0.u = wA[kb * 4];     xa1.u = wA[kb * 4 + 1];
            xa2.u = wA[kb * 4 + 2]; xa3.u = wA[kb * 4 + 3];
            xb0.u = wB[kb * 4];     xb1.u = wB[kb * 4 + 1];
            xb2.u = wB[kb * 4 + 2]; xb3.u = wB[kb * 4 + 3];
#if __has_builtin(__builtin_amdgcn_fdot2)
            a0 = __builtin_amdgcn_fdot2(h0.v, xa0.v, a0, false);
            a1 = __builtin_amdgcn_fdot2(h1.v, xa1.v, a1, false);
            a2 = __builtin_amdgcn_fdot2(h2.v, xa2.v, a2, false);
            a3 = __builtin_amdgcn_fdot2(h3.v, xa3.v, a3, false);
            b0 = __builtin_amdgcn_fdot2(h0.v, xb0.v, b0, false);
            b1 = __builtin_amdgcn_fdot2(h1.v, xb1.v, b1, false);
            b2 = __builtin_amdgcn_fdot2(h2.v, xb2.v, b2, false);
            b3 = __builtin_amdgcn_fdot2(h3.v, xb3.v, b3, false);
#else
            a0 = fmaf((float)h0.v[0], (float)xa0.v[0], fmaf((float)h0.v[1], (float)xa0.v[1], a0));
            a1 = fmaf((float)h1.v[0], (float)xa1.v[0], fmaf((float)h1.v[1], (float)xa1.v[1], a1));
            a2 = fmaf((float)h2.v[0], (float)xa2.v[0], fmaf((float)h2.v[1], (float)xa2.v[1], a2));
            a3 = fmaf((float)h3.v[0], (float)xa3.v[0], fmaf((float)h3.v[1], (float)xa3.v[1], a3));
            b0 = fmaf((float)h0.v[0], (float)xb0.v[0], fmaf((float)h0.v[1], (float)xb0.v[1], b0));
            b1 = fmaf((float)h1.v[0], (float)xb1.v[0], fmaf((float)h1.v[1], (float)xb1.v[1], b1));
            b2 = fmaf((float)h2.v[0], (float)xb2.v[0], fmaf((float)h2.v[1], (float)xb2.v[1], b2));
            b3 = fmaf((float)h3.v[0], (float)xb3.v[0], fmaf((float)h3.v[1], (float)xb3.v[1], b3));
#endif
        }
        float pre0 = xc0 + ((a0 + a1) + (a2 + a3));   // gate g0
        float pre1 = xc1 + ((b0 + b1) + (b2 + b3));   // gate g1
        float sA = __shfl_xor(pre0, 1);               // partner's g0
        float sB = __shfl_xor(pre1, 1);               // partner's g1
        float gi = gp ? sA : pre0;
        float gf = gp ? sB : pre1;
        float gg = gp ? pre0 : sA;
        float go = gp ? pre1 : sB;
        c = fsig(gf) * c + fsig(gi) * ftanh(gg);
        float hval = fsig(go) * ftanh(c);
        int nxt = cur ^ 1;
        if (gp == 0) {
            ((_Float16*)&hsm[nxt][0])[ch] = (_Float16)hval;
            hb[s * H + ch] = hval;
        }
        __syncthreads();
        cur = nxt;
    }
}

// ---------------------------------------------------------------------------
// k_amp_kprep (round-12 fusion): blocks 0-31 = amp, 32-287 = kprep.
// ---------------------------------------------------------------------------
__global__ __launch_bounds__(256) void k_amp_kprep(const float* __restrict__ hs,
                                                   const float* __restrict__ audio,
                                                   const float* __restrict__ video,
                                                   const float* __restrict__ pW, const float* __restrict__ pb,
                                                   const float* __restrict__ aW1, const float* __restrict__ ab1,
                                                   const float* __restrict__ aW2, const float* __restrict__ ab2,
                                                   const float* __restrict__ aW3, const float* __restrict__ ab3,
                                                   const float* __restrict__ vW1, const float* __restrict__ vb1,
                                                   const float* __restrict__ vW2, const float* __restrict__ vb2,
                                                   const float* __restrict__ vW3, const float* __restrict__ vb3,
                                                   float* __restrict__ ampT, float* __restrict__ ampA,
                                                   float* __restrict__ ampV,
                                                   const float* __restrict__ kr,
                                                   const float* __restrict__ ki,
                                                   unsigned short* __restrict__ Bh) {
    __shared__ float sPW[16 * 128], sA1[16 * 74], sV1[16 * 35];
    __shared__ float sA2[256], sA3[256], sV2[256], sV3[256];
    __shared__ float sbp[16], sba1[16], sba2[16], sba3[16], sbv1[16], sbv2[16], sbv3[16];
    __shared__ float red[256];
    int tid = threadIdx.x;

    if (blockIdx.x >= 32) {
        // ---- kprep: normalize K, build bf16 B (hi only) ----
        int u = blockIdx.x - 32;
        const float* r0 = kr + (size_t)u * Mdim;
        const float* i0 = ki + (size_t)u * Mdim;
        float ss = 0.f;
        for (int d = tid; d < Mdim; d += 256) {
            float a = r0[d], b2 = i0[d];
            ss = fmaf(a, a, fmaf(b2, b2, ss));
        }
        red[tid] = ss; __syncthreads();
        for (int off = 128; off > 0; off >>= 1) {
            if (tid < off) red[tid] += red[tid + off];
            __syncthreads();
        }
        float inv = 1.f / sqrtf(red[0]);
        for (int d = tid; d < Mdim; d += 256) {
            float xr = r0[d] * inv, xi = i0[d] * inv;
            unsigned short hr = f2bf(xr);
            unsigned short hi_ = f2bf(xi);
            int ch = d >> 5;
            int kl = (d & 31) * 2;
            size_t base = ((size_t)ch * 512 + 2 * u) * 64 + kl;     // row 2u
            Bh[base] = hr;  Bh[base + 1] = hi_;
            size_t base2 = base + 64;                                // row 2u+1
            Bh[base2] = hi_ ^ 0x8000; Bh[base2 + 1] = hr;
        }
        return;
    }

    // ---- amp ----
    for (int i = tid; i < 16 * 128; i += 256) sPW[i] = pW[i];
    for (int i = tid; i < 16 * 74; i += 256) sA1[i] = aW1[i];
    for (int i = tid; i < 16 * 35; i += 256) sV1[i] = vW1[i];
    if (tid < 256) { sA2[tid] = aW2[tid]; sA3[tid] = aW3[tid]; sV2[tid] = vW2[tid]; sV3[tid] = vW3[tid]; }
    if (tid < 16) {
        sbp[tid] = pb[tid];
        sba1[tid] = ab1[tid]; sba2[tid] = ab2[tid]; sba3[tid] = ab3[tid];
        sbv1[tid] = vb1[tid]; sbv2[tid] = vb2[tid]; sbv3[tid] = vb3[tid];
    }
    __syncthreads();
    int t = blockIdx.x * 256 + tid;

    const float* hrow = hs + (size_t)t * H;
    float accT[16];
#pragma unroll
    for (int m = 0; m < 16; m++) accT[m] = sbp[m];
    for (int k = 0; k < 128; k += 4) {
        float4 hv = *(const float4*)&hrow[k];
#pragma unroll
        for (int m = 0; m < 16; m++) {
            float4 wv = *(const float4*)&sPW[m * 128 + k];
            accT[m] = fmaf(hv.x, wv.x, fmaf(hv.y, wv.y, fmaf(hv.z, wv.z, fmaf(hv.w, wv.w, accT[m]))));
        }
    }
#pragma unroll
    for (int m = 0; m < 16; m++) ampT[t * 16 + m] = accT[m];

    float y1[16], y2[16];
    const float* arow = audio + (size_t)t * DA;
#pragma unroll 4
    for (int m = 0; m < 16; m++) {
        float a = sba1[m];
        for (int k = 0; k < DA; k++) a = fmaf(arow[k], sA1[m * DA + k], a);
        y1[m] = fmaxf(a, 0.f);
    }
#pragma unroll
    for (int m = 0; m < 16; m++) {
        float a = sba2[m];
#pragma unroll
        for (int k = 0; k < 16; k++) a = fmaf(y1[k], sA2[m * 16 + k], a);
        y2[m] = fmaxf(a, 0.f);
    }
#pragma unroll
    for (int m = 0; m < 16; m++) {
        float a = sba3[m];
#pragma unroll
        for (int k = 0; k < 16; k++) a = fmaf(y2[k], sA3[m * 16 + k], a);
        ampA[t * 16 + m] = fmaxf(a, 0.f);
    }
    const float* vrow = video + (size_t)t * DV;
#pragma unroll 4
    for (int m = 0; m < 16; m++) {
        float a = sbv1[m];
        for (int k = 0; k < DV; k++) a = fmaf(vrow[k], sV1[m * DV + k], a);
        y1[m] = fmaxf(a, 0.f);
    }
#pragma unroll
    for (int m = 0; m < 16; m++) {
        float a = sbv2[m];
#pragma unroll
        for (int k = 0; k < 16; k++) a = fmaf(y1[k], sV2[m * 16 + k], a);
        y2[m] = fmaxf(a, 0.f);
    }
#pragma unroll
    for (int m = 0; m < 16; m++) {
        float a = sbv3[m];
#pragma unroll
        for (int k = 0; k < 16; k++) a = fmaf(y2[k], sV3[m * 16 + k], a);
        ampV[t * 16 + m] = fmaxf(a, 0.f);
    }
}

// ---------------------------------------------------------------------------
// k_modality: per-b: norms, softmax over S, weight, z = a_n * e^{i phase}.
// ---------------------------------------------------------------------------
__global__ __launch_bounds__(128) void k_modality(const int* __restrict__ idx,
                                                  const float* __restrict__ pt,
                                                  const float* __restrict__ ampT,
                                                  const float* __restrict__ ampA,
                                                  const float* __restrict__ ampV,
                                                  const float* __restrict__ mweights,
                                                  float* __restrict__ zq, float* __restrict__ wt) {
    int b = blockIdx.x, s = threadIdx.x;
    __shared__ float red[128];
    int t = b * S + s;
    const float* amps0 = ampT + (size_t)t * 16;
    const float* amps1 = ampA + (size_t)t * 16;
    const float* amps2 = ampV + (size_t)t * 16;

    float m0 = mweights[0], m1 = mweights[1], m2 = mweights[2];
    float mx = fmaxf(m0, fmaxf(m1, m2));
    float e0 = expf(m0 - mx), e1 = expf(m1 - mx), e2 = expf(m2 - mx);
    float es = e0 + e1 + e2;
    float mw[3] = {e0 / es, e1 / es, e2 / es};

    int row = idx[t];
    float wacc = 0.f;
    for (int m = 0; m < 3; m++) {
        const float* amp = (m == 0) ? amps0 : (m == 1) ? amps1 : amps2;
        float av[16];
        float ss = 0.f;
#pragma unroll
        for (int c2 = 0; c2 < 16; c2++) { av[c2] = amp[c2]; ss = fmaf(av[c2], av[c2], ss); }
        float nrm = sqrtf(ss);
        red[s] = nrm; __syncthreads();
        for (int off = 64; off > 0; off >>= 1) {
            if (s < off) red[s] = fmaxf(red[s], red[s + off]);
            __syncthreads();
        }
        float rmax = red[0]; __syncthreads();
        float ex = expf(nrm - rmax);
        red[s] = ex; __syncthreads();
        for (int off = 64; off > 0; off >>= 1) {
            if (s < off) red[s] += red[s + off];
            __syncthreads();
        }
        float rsum = red[0]; __syncthreads();
        wacc = fmaf(mw[m], ex / rsum, wacc);

        float inv = 1.f / nrm;
        const float* ph = pt + ((size_t)m * V + row) * 16;
        float2* zdst = (float2*)zq + ((size_t)m * T_ + t) * 16;
#pragma unroll
        for (int c2 = 0; c2 < 16; c2++) {
            float an = av[c2] * inv;
            float p = ph[c2];
            zdst[c2] = make_float2(cosf(p) * an, sinf(p) * an);
        }
    }
    wt[t] = wacc;
}

// ---------------------------------------------------------------------------
// k_gmalpha v4 (round-16): one change vs round-14 — alpha's zs row stride
// 34->33 floats shrinks LDS 52224->50688 B (3x50688=152064 <= 163840) and
// launch_bounds (256,2)->(256,3): target 3 blocks/CU instead of 2. Stride-33
// bank check: staging writes consecutive (conflict-free); zst reads are
// same-address broadcasts across half-waves. Math bit-identical.
// ---------------------------------------------------------------------------
__global__ __launch_bounds__(256, 3) void k_gmalpha(const float* __restrict__ zq,
                                                    const unsigned short* __restrict__ Bh,
                                                    unsigned int* __restrict__ Gt32,
                                                    unsigned int* __restrict__ ahq,
                                                    unsigned int* __restrict__ alq) {
    __shared__ __align__(16) unsigned char smem[50688];
    int tid = threadIdx.x;

    if (blockIdx.x < 512) {
        // ================= Gm =================
        unsigned short (*Ah)[72] = (unsigned short (*)[72])smem;                 // 64 rows
        unsigned short (*Bhs)[72] = (unsigned short (*)[72])(smem + 64 * 72 * 2); // 128 rows
        int xcd = blockIdx.x & 7;
        int nt = xcd >> 1;                            // panel pinned per XCD pair
        int mt = ((blockIdx.x >> 3) << 1) | (xcd & 1);
        int t0 = mt * 64, n0 = nt * 128;

        int tl = tid >> 2, qf = tid & 3;
        int tok = t0 + tl;
        int h = qf >> 1;
        int d3b = (qf & 1) * 8;
        const float2* zq2 = (const float2*)zq;
        float z3r[8], z3i[8];
#pragma unroll
        for (int j = 0; j < 8; j++) {
            float2 v = zq2[((size_t)2 * T_ + tok) * 16 + d3b + j];
            z3r[j] = v.x; z3i[j] = v.y;
        }

        int wid = tid >> 6, lane = tid & 63;
        int wn = wid >> 1, wt2 = wid & 1;
        int lrow = lane & 15, lk = lane >> 4;

        f32x4 acc[4][2];
#pragma unroll
        for (int fm = 0; fm < 4; fm++)
#pragma unroll
            for (int fn = 0; fn < 2; fn++) acc[fm][fn] = (f32x4){0.f, 0.f, 0.f, 0.f};

        union S8 { short8v v; unsigned short u[8]; };

        for (int ch = 0; ch < NCH; ch++) {
            const unsigned short* srcH = Bh + ((size_t)ch * 512 + n0) * 64;
            uint4 bvh[4];
#pragma unroll
            for (int l = 0; l < 4; l++) {
                int i2 = tid + 256 * l;
                bvh[l] = *(const uint4*)(srcH + (size_t)i2 * 8);
            }

            int d1 = ch >> 3;
            int d2 = ((ch & 7) << 1) + h;
            float2 z1 = zq2[(size_t)tok * 16 + d1];
            float2 z2 = zq2[((size_t)T_ + tok) * 16 + d2];
            float w1r = z1.x - z1.y, w1i = z1.x + z1.y;
            float wr_ = w1r * z2.x - w1i * z2.y;
            float wi_ = w1r * z2.y + w1i * z2.x;
            S8 h0, h1;
#pragma unroll
            for (int j = 0; j < 8; j++) {
                float pr_ = wr_ * z3r[j] - wi_ * z3i[j];
                float pi_ = wr_ * z3i[j] + wi_ * z3r[j];
                unsigned short phr = f2bf(pr_);
                unsigned short phi = f2bf(pi_);
                if (j < 4) {
                    h0.u[2 * j] = phr;     h0.u[2 * j + 1] = phi;
                } else {
                    h1.u[2 * (j - 4)] = phr; h1.u[2 * (j - 4) + 1] = phi;
                }
            }
            int aoff = h * 32 + (qf & 1) * 16;
            *(short8v*)&Ah[tl][aoff] = h0.v;
            *(short8v*)&Ah[tl][aoff + 8] = h1.v;

#pragma unroll
            for (int l = 0; l < 4; l++) {
                int i2 = tid + 256 * l;
                *(uint4*)&Bhs[i2 >> 3][(i2 & 7) * 8] = bvh[l];
            }
            __syncthreads();

#pragma unroll
            for (int kk = 0; kk < 2; kk++) {
                short8v kf[4], ahf[2];
#pragma unroll
                for (int fm = 0; fm < 4; fm++) {
                    int nr = wn * 64 + fm * 16 + lrow;
                    int co = kk * 32 + lk * 8;
                    kf[fm] = *(const short8v*)&Bhs[nr][co];
                }
#pragma unroll
                for (int fn = 0; fn < 2; fn++) {
                    int ro = wt2 * 32 + fn * 16 + lrow;
                    int co = kk * 32 + lk * 8;
                    ahf[fn] = *(const short8v*)&Ah[ro][co];
                }
#pragma unroll
                for (int fm = 0; fm < 4; fm++)
#pragma unroll
                    for (int fn = 0; fn < 2; fn++)
                        acc[fm][fn] = __builtin_amdgcn_mfma_f32_16x16x32_bf16(kf[fm], ahf[fn], acc[fm][fn], 0, 0, 0);
            }
            __syncthreads();
        }

#pragma unroll
        for (int fm = 0; fm < 4; fm++)
#pragma unroll
            for (int fn = 0; fn < 2; fn++) {
                int t = t0 + wt2 * 32 + fn * 16 + lrow;
                int bb = t >> 7, tl2 = t & 127;
#pragma unroll
                for (int p = 0; p < 2; p++) {
                    int ng = n0 + wn * 64 + fm * 16 + lk * 4 + 2 * p;
                    float vr = acc[fm][fn][2 * p];
                    float vi = acc[fm][fn][2 * p + 1];
                    unsigned int evenw = (unsigned int)f2bf(vr) | ((unsigned int)f2bf(-vi) << 16);
                    unsigned int oddw  = (unsigned int)f2bf(vi) | ((unsigned int)f2bf(vr) << 16);
                    Gt32[((size_t)bb * 512 + ng) * 128 + tl2] = evenw;
                    Gt32[((size_t)bb * 512 + ng + 1) * 128 + tl2] = oddw;
                }
            }
        return;
    }

    // ================= alpha =================
    float* zs = (float*)smem;     // 3*128*33 floats = 50688 B
    int bidx = blockIdx.x - 512;
    int b = bidx >> 3, s0 = (bidx & 7) * 16;
    int sl = tid >> 4, tg = tid & 15;

    for (int i = tid; i < 3 * 128 * 32; i += 256) {
        int m = i >> 12;
        int rem = i & 4095;
        int tok = rem >> 5, jj = rem & 31;
        zs[(m * 128 + tok) * 33 + jj] = zq[((size_t)m * T_ + b * S) * 32 + rem];
    }
    __syncthreads();

    int s = s0 + sl;
    float pr[8], pi[8];
#pragma unroll
    for (int j = 0; j < 8; j++) { pr[j] = 1.f; pi[j] = 0.f; }
    for (int m = 0; m < 3; m++) {
        float sr_[16], si_[16];
        const float* zss = &zs[(m * 128 + s) * 33];
#pragma unroll
        for (int c2 = 0; c2 < 16; c2++) { sr_[c2] = zss[2 * c2]; si_[c2] = zss[2 * c2 + 1]; }
#pragma unroll
        for (int j = 0; j < 8; j++) {
            int t = tg + 16 * j;
            const float* zst = &zs[(m * 128 + t) * 33];
            float dr = 0.f, di = 0.f;
#pragma unroll
            for (int c2 = 0; c2 < 16; c2++) {
                float br_ = zst[2 * c2], bi_ = zst[2 * c2 + 1];
                dr = fmaf(sr_[c2], br_, fmaf(-si_[c2], bi_, dr));
                di = fmaf(sr_[c2], bi_, fmaf(si_[c2], br_, di));
            }
            float nr = pr[j] * dr - pi[j] * di;
            float ni = pr[j] * di + pi[j] * dr;
            pr[j] = nr; pi[j] = ni;
        }
    }
    float ur[8], ui[8];
#pragma unroll
    for (int j = 0; j < 8; j++) { ur[j] = -2.f * pi[j]; ui[j] = 2.f * pr[j]; }

    float mr = ur[0], mi_ = ui[0];
#pragma unroll
    for (int j = 1; j < 8; j++) { mr = fmaxf(mr, ur[j]); mi_ = fmaxf(mi_, ui[j]); }
    for (int off = 1; off < 16; off <<= 1) {
        mr = fmaxf(mr, __shfl_xor(mr, off));
        mi_ = fmaxf(mi_, __shfl_xor(mi_, off));
    }
    float sr = 0.f, si = 0.f;
#pragma unroll
    for (int j = 0; j < 8; j++) {
        ur[j] = expf(ur[j] - mr); sr += ur[j];
        ui[j] = expf(ui[j] - mi_); si += ui[j];
    }
    for (int off = 1; off < 16; off <<= 1) {
        sr += __shfl_xor(sr, off);
        si += __shfl_xor(si, off);
    }
    float invr = 1.f / sr, invi = 1.f / si;
    unsigned int* ah_ = ahq + ((size_t)b * S + s) * 128;
    unsigned int* al_ = alq + ((size_t)b * S + s) * 128;
#pragma unroll
    for (int j = 0; j < 8; j++) {
        int t = tg + 16 * j;
        float arj = ur[j] * invr;
        float aij = ui[j] * invi;
        if (t == s) arj += 1.f;
        unsigned short rh = f2bf(arj), ih = f2bf(aij);
        unsigned short rl = f2bf(arj - bf2f(rh)), il = f2bf(aij - bf2f(ih));
        ah_[t] = (unsigned int)rh | ((unsigned int)ih << 16);
        al_[t] = (unsigned int)rl | ((unsigned int)il << 16);
    }
}

// ---------------------------------------------------------------------------
// k_meas_mfma: per-batch real GEMM in = A' @ Gt^T via MFMA; epilogue
// meas[b,u] = sum_s w[s]*(in[s,2u]^2 + in[s,2u+1]^2).
// ---------------------------------------------------------------------------
__global__ __launch_bounds__(256, 2) void k_meas_mfma(const unsigned short* __restrict__ Aq,
                                                      const unsigned short* __restrict__ Alq,
                                                      const unsigned short* __restrict__ Gt,
                                                      const float* __restrict__ wt,
                                                      float* __restrict__ meas) {
    int tid = threadIdx.x;
    int b = blockIdx.x >> 2, nq = blockIdx.x & 3;
    int wid = tid >> 6, lane = tid & 63;
    int ws = wid >> 1, wn2 = wid & 1;
    int lrow = lane & 15, lk = lane >> 4;

    f32x4 acc[4][4];
#pragma unroll
    for (int fm = 0; fm < 4; fm++)
#pragma unroll
        for (int fn = 0; fn < 4; fn++) acc[fm][fn] = (f32x4){0.f, 0.f, 0.f, 0.f};

    const unsigned short* Ab = Aq + (size_t)b * 128 * 256;
    const unsigned short* Alb = Alq + (size_t)b * 128 * 256;
    const unsigned short* Gb = Gt + (size_t)b * 512 * 256;

    for (int kc = 0; kc < 8; kc++) {
        int ko = kc * 32 + lk * 8;
        short8v ah[4], al[4], bt[4];
#pragma unroll
        for (int fm = 0; fm < 4; fm++) {
            int s = ws * 64 + fm * 16 + lrow;
            ah[fm] = *(const short8v*)(Ab + (size_t)s * 256 + ko);
            al[fm] = *(const short8v*)(Alb + (size_t)s * 256 + ko);
        }
#pragma unroll
        for (int fn = 0; fn < 4; fn++) {
            int n = nq * 128 + wn2 * 64 + fn * 16 + lrow;
            bt[fn] = *(const short8v*)(Gb + (size_t)n * 256 + ko);
        }
#pragma unroll
        for (int fm = 0; fm < 4; fm++)
#pragma unroll
            for (int fn = 0; fn < 4; fn++) {
                acc[fm][fn] = __builtin_amdgcn_mfma_f32_16x16x32_bf16(ah[fm], bt[fn], acc[fm][fn], 0, 0, 0);
                acc[fm][fn] = __builtin_amdgcn_mfma_f32_16x16x32_bf16(al[fm], bt[fn], acc[fm][fn], 0, 0, 0);
            }
    }

    __shared__ float red[4][4][16];
    float part[4] = {0.f, 0.f, 0.f, 0.f};
#pragma unroll
    for (int fm = 0; fm < 4; fm++)
#pragma unroll
        for (int j = 0; j < 4; j++) {
            int s = ws * 64 + fm * 16 + lk * 4 + j;
            float w = wt[b * S + s];
#pragma unroll
            for (int fn = 0; fn < 4; fn++) {
                float v = acc[fm][fn][j];
                part[fn] = fmaf(w * v, v, part[fn]);
            }
        }
#pragma unroll
    for (int fn = 0; fn < 4; fn++) {
        part[fn] += __shfl_xor(part[fn], 16);
        part[fn] += __shfl_xor(part[fn], 32);
    }
    if (lane < 16) {
#pragma unroll
        for (int fn = 0; fn < 4; fn++) red[wid][fn][lane] = part[fn];
    }
    __syncthreads();
    if (tid < 64) {
        int n0 = 2 * tid;
        int wn2a = n0 >> 6, rem = n0 & 63, fna = rem >> 4, ca = rem & 15;
        float v = red[wn2a][fna][ca] + red[2 + wn2a][fna][ca]
                + red[wn2a][fna][ca + 1] + red[2 + wn2a][fna][ca + 1];
        meas[(size_t)b * UNITS + nq * 64 + tid] = v;
    }
}

// ---------------------------------------------------------------------------
// k_head: 3-layer MLP head.
// ---------------------------------------------------------------------------
__global__ __launch_bounds__(64) void k_head(const float* __restrict__ meas,
                                             const float* __restrict__ fc1W, const float* __restrict__ fc1b,
                                             const float* __restrict__ fc2W, const float* __restrict__ fc2b,
                                             const float* __restrict__ fc3W, const float* __restrict__ fc3b,
                                             float* __restrict__ out) {
    int b = blockIdx.x, j = threadIdx.x;
    __shared__ float y[64];
    float a = fc1b[j];
    for (int u = 0; u < 256; u++) a = fmaf(meas[(size_t)b * 256 + u], fc1W[j * 256 + u], a);
    y[j] = fmaxf(a, 0.f);
    __syncthreads();
    float a2 = fc2b[j];
#pragma unroll
    for (int k = 0; k < 64; k++) a2 = fmaf(y[k], fc2W[j * 64 + k], a2);
    a2 = fmaxf(a2, 0.f);
    float v = a2 * fc3W[j];
    for (int off = 32; off > 0; off >>= 1) v += __shfl_down(v, off);
    if (j == 0) out[b] = v + fc3b[0];
}

// ---------------------------------------------------------------------------
extern "C" void kernel_launch(void* const* d_in, const int* in_sizes, int n_in,
                              void* d_out, int out_size, void* d_ws, size_t ws_size,
                              hipStream_t stream) {
    const int* text_idx = (const int*)d_in[0];
    const float* audio = (const float*)d_in[1];
    const float* video = (const float*)d_in[2];
    const float* emb = (const float*)d_in[3];
    const float* pt = (const float*)d_in[4];
    const float* Wih = (const float*)d_in[5];
    const float* Whh = (const float*)d_in[6];
    const float* bih = (const float*)d_in[7];
    const float* bhh = (const float*)d_in[8];
    const float* pW = (const float*)d_in[9];
    const float* pb = (const float*)d_in[10];
    const float* aW1 = (const float*)d_in[11];
    const float* ab1 = (const float*)d_in[12];
    const float* aW2 = (const float*)d_in[13];
    const float* ab2 = (const float*)d_in[14];
    const float* aW3 = (const float*)d_in[15];
    const float* ab3 = (const float*)d_in[16];
    const float* vW1 = (const float*)d_in[17];
    const float* vb1 = (const float*)d_in[18];
    const float* vW2 = (const float*)d_in[19];
    const float* vb2 = (const float*)d_in[20];
    const float* vW3 = (const float*)d_in[21];
    const float* vb3 = (const float*)d_in[22];
    const float* mweights = (const float*)d_in[23];
    const float* mkr = (const float*)d_in[24];
    const float* mki = (const float*)d_in[25];
    const float* fc1W = (const float*)d_in[26];
    const float* fc1b = (const float*)d_in[27];
    const float* fc2W = (const float*)d_in[28];
    const float* fc2b = (const float*)d_in[29];
    const float* fc3W = (const float*)d_in[30];
    const float* fc3b = (const float*)d_in[31];

    float* ws = (float*)d_ws;
    size_t off = 0;
    float* hs = ws + off;   off += (size_t)T_ * H;          // 4 MB
    float* xW = ws + off;   off += (size_t)T_ * 512;        // 16 MB; reused as Gt
    float* ampT = ws + off; off += (size_t)T_ * 16;
    float* ampA = ws + off; off += (size_t)T_ * 16;
    float* ampV = ws + off; off += (size_t)T_ * 16;
    float* zq = ws + off;   off += (size_t)3 * T_ * 32;     // 3 MB
    float* wt = ws + off;   off += (size_t)T_;
    unsigned short* BhW = (unsigned short*)(ws + off); off += (size_t)2097152;  // 8 MB
    unsigned int* ahq = (unsigned int*)(ws + off); off += (size_t)1048576;      // 4 MB
    unsigned int* alq = (unsigned int*)(ws + off); off += (size_t)1048576;      // 4 MB
    float* meas = ws + off; off += (size_t)B * UNITS;
    (void)ws_size; (void)in_sizes; (void)n_in; (void)out_size;

    k_embed<<<256, 256, 0, stream>>>(text_idx, emb, Wih, bih, bhh, xW);
    k_lstm<<<B, 256, 0, stream>>>(xW, Whh, hs);
    k_amp_kprep<<<288, 256, 0, stream>>>(hs, audio, video, pW, pb,
                                         aW1, ab1, aW2, ab2, aW3, ab3,
                                         vW1, vb1, vW2, vb2, vW3, vb3,
                                         ampT, ampA, ampV,
                                         mkr, mki, BhW);
    k_modality<<<B, 128, 0, stream>>>(text_idx, pt, ampT, ampA, ampV, mweights, zq, wt);
    k_gmalpha<<<1024, 256, 0, stream>>>(zq, BhW, (unsigned int*)xW /* = Gt */, ahq, alq);
    k_meas_mfma<<<256, 256, 0, stream>>>((const unsigned short*)ahq,
                                         (const unsigned short*)alq,
                                         (const unsigned short*)xW /* Gt */,
                                         wt, meas);
    k_head<<<B, 64, 0, stream>>>(meas, fc1W, fc1b, fc2W, fc2b, fc3W, fc3b, (float*)d_out);
}

// Round 17
// 377.292 us; speedup vs baseline: 1.0390x; 1.0390x over previous
//
#include <hip/hip_runtime.h>
#include <math.h>

constexpr int B = 64, S = 128, V = 5000;
constexpr int DT = 300, DA = 74, DV = 35;
constexpr int H = 128, C16 = 16;
constexpr int Mdim = 4096, UNITS = 256;
constexpr int T_ = B * S;   // 8192 tokens
constexpr int NCH = 128;    // K-chunks of 32 complex (64 real) in Gm

typedef __attribute__((ext_vector_type(8))) short short8v;
typedef __attribute__((ext_vector_type(4))) float f32x4;
typedef _Float16 half2v __attribute__((ext_vector_type(2)));

__device__ __forceinline__ unsigned short f2bf(float x) {
    unsigned int u = __float_as_uint(x);
    unsigned int r = (u + 0x7fffu + ((u >> 16) & 1u)) >> 16;
    return (unsigned short)r;
}
__device__ __forceinline__ float bf2f(unsigned short h) {
    return __uint_as_float(((unsigned int)h) << 16);
}
__device__ __forceinline__ float fsig(float x) { return 1.f / (1.f + __expf(-x)); }
__device__ __forceinline__ float ftanh(float x) {
    float t = __expf(2.f * x);
    return (t - 1.f) / (t + 1.f);
}

union U2 { unsigned int u; half2v v; };

// ---------------------------------------------------------------------------
// k_embed: xW[token, j] = emb[idx[token]] @ Wih.T + bih + bhh   (8192 x 512)
// ---------------------------------------------------------------------------
__global__ __launch_bounds__(256, 2) void k_embed(const int* __restrict__ idx,
                                                  const float* __restrict__ emb,
                                                  const float* __restrict__ Wih,
                                                  const float* __restrict__ bih,
                                                  const float* __restrict__ bhh,
                                                  float* __restrict__ xW) {
    __shared__ float As[60][132];   // [kk][token]
    __shared__ float Ws[60][132];   // [kk][j]
    __shared__ int sidx[128];
    int tid = threadIdx.x;
    int t0 = (blockIdx.x >> 2) * 128;
    int j0 = (blockIdx.x & 3) * 128;
    if (tid < 128) sidx[tid] = idx[t0 + tid];

    int jq = tid & 15, tq = tid >> 4;
    float acc[8][8];
#pragma unroll
    for (int r = 0; r < 8; r++)
#pragma unroll
        for (int cc = 0; cc < 8; cc++) acc[r][cc] = 0.f;

    __syncthreads();
    for (int c = 0; c < 5; c++) {
        int k0 = c * 60;
        if (c) __syncthreads();
        for (int i = tid; i < 128 * 60; i += 256) {
            int tok = i / 60, kk = i - tok * 60;
            As[kk][tok] = emb[(size_t)sidx[tok] * 300 + k0 + kk];
            Ws[kk][tok] = Wih[(size_t)(j0 + tok) * 300 + k0 + kk];
        }
        __syncthreads();
#pragma unroll 4
        for (int kk = 0; kk < 60; kk++) {
            float4 a0 = *(const float4*)&As[kk][tq * 8];
            float4 a1 = *(const float4*)&As[kk][tq * 8 + 4];
            float4 w0 = *(const float4*)&Ws[kk][jq * 8];
            float4 w1 = *(const float4*)&Ws[kk][jq * 8 + 4];
            float a[8] = {a0.x, a0.y, a0.z, a0.w, a1.x, a1.y, a1.z, a1.w};
            float w[8] = {w0.x, w0.y, w0.z, w0.w, w1.x, w1.y, w1.z, w1.w};
#pragma unroll
            for (int r = 0; r < 8; r++)
#pragma unroll
                for (int cc = 0; cc < 8; cc++)
                    acc[r][cc] = fmaf(a[r], w[cc], acc[r][cc]);
        }
    }
    float bb[8];
#pragma unroll
    for (int cc = 0; cc < 8; cc++) {
        int j = j0 + jq * 8 + cc;
        bb[cc] = bih[j] + bhh[j];
    }
#pragma unroll
    for (int r = 0; r < 8; r++) {
        int t = t0 + tq * 8 + r;
        float4 o0, o1;
        o0.x = acc[r][0] + bb[0]; o0.y = acc[r][1] + bb[1];
        o0.z = acc[r][2] + bb[2]; o0.w = acc[r][3] + bb[3];
        o1.x = acc[r][4] + bb[4]; o1.y = acc[r][5] + bb[5];
        o1.z = acc[r][6] + bb[6]; o1.w = acc[r][7] + bb[7];
        *(float4*)&xW[(size_t)t * 512 + j0 + jq * 8] = o0;
        *(float4*)&xW[(size_t)t * 512 + j0 + jq * 8 + 4] = o1;
    }
}

// ---------------------------------------------------------------------------
// k_lstm v5 (round-15 winner): 256 threads, 2 gate-rows per thread.
// ---------------------------------------------------------------------------
__global__ __launch_bounds__(256) void k_lstm(const float* __restrict__ xW,
                                              const float* __restrict__ Whh,
                                              float* __restrict__ hs) {
    __shared__ __align__(16) unsigned int hsm[2][64];   // 128 fp16 channels, packed
    int b = blockIdx.x, tid = threadIdx.x;
    int ch = tid >> 1, gp = tid & 1;    // gp0: gates {0,1}=i,f ; gp1: {2,3}=g,o
    int g0 = gp * 2, g1 = gp * 2 + 1;

    unsigned int wA[64], wB[64];
    const float* wr0 = Whh + (size_t)(g0 * 128 + ch) * 128;
    const float* wr1 = Whh + (size_t)(g1 * 128 + ch) * 128;
#pragma unroll
    for (int k = 0; k < 64; k++) {
        U2 t;
        t.v[0] = (_Float16)wr0[2 * k];
        t.v[1] = (_Float16)wr0[2 * k + 1];
        wA[k] = t.u;
        U2 u;
        u.v[0] = (_Float16)wr1[2 * k];
        u.v[1] = (_Float16)wr1[2 * k + 1];
        wB[k] = u.u;
    }
    if (tid < 64) { hsm[0][tid] = 0u; hsm[1][tid] = 0u; }

    const float* xwb = xW + (size_t)b * S * 512;
    float* hb = hs + (size_t)b * S * H;
    int gch0 = g0 * 128 + ch, gch1 = g1 * 128 + ch;
    float xn0 = xwb[gch0], xn1 = xwb[gch1];
    float c = 0.f;
    __syncthreads();

    int cur = 0;
    for (int s = 0; s < S; s++) {
        float xc0 = xn0, xc1 = xn1;
        if (s + 1 < S) {
            xn0 = xwb[(size_t)(s + 1) * 512 + gch0];
            xn1 = xwb[(size_t)(s + 1) * 512 + gch1];
        }
        float a0 = 0.f, a1 = 0.f, a2 = 0.f, a3 = 0.f;
        float b0 = 0.f, b1 = 0.f, b2 = 0.f, b3 = 0.f;
#pragma unroll
        for (int kb = 0; kb < 16; kb++) {
            uint4 hv = *(const uint4*)&hsm[cur][kb * 4];
            U2 h0, h1, h2, h3;
            h0.u = hv.x; h1.u = hv.y; h2.u = hv.z; h3.u = hv.w;
            U2 xa0, xa1, xa2, xa3, xb0, xb1, xb2, xb3;
            xa0.u = wA[kb * 4];     xa1.u = wA[kb * 4 + 1];
            xa2.u = wA[kb * 4 + 2]; xa3.u = wA[kb * 4 + 3];
            xb0.u = wB[kb * 4];     xb1.u = wB[kb * 4 + 1];
            xb2.u = wB[kb * 4 + 2]; xb3.u = wB[kb * 4 + 3];
#if __has_builtin(__builtin_amdgcn_fdot2)
            a0 = __builtin_amdgcn_fdot2(h0.v, xa0.v, a0, false);
            a1 = __builtin_amdgcn_fdot2(h1.v, xa1.v, a1, false);
            a2 = __builtin_amdgcn_fdot2(h2.v, xa2.v, a2, false);
            a3 = __builtin_amdgcn_fdot2(h3.v, xa3.v, a3, false);
            b0 = __builtin_amdgcn_fdot2(h0.v, xb0.v, b0, false);
            b1 = __builtin_amdgcn_fdot2(h1.v, xb1.v, b1, false);
            b2 = __builtin_amdgcn_fdot2(h2.v, xb2.v, b2, false);
            b3 = __builtin_amdgcn_fdot2(h3.v, xb3.v, b3, false);
#else
            a0 = fmaf((float)h0.v[0], (float)xa0.v[0], fmaf((float)h0.v[1], (float)xa0.v[1], a0));
            a1 = fmaf((float)h1.v[0], (float)xa1.v[0], fmaf((float)h1.v[1], (float)xa1.v[1], a1));
            a2 = fmaf((float)h2.v[0], (float)xa2.v[0], fmaf((float)h2.v[1], (float)xa2.v[1], a2));
            a3 = fmaf((float)h3.v[0], (float)xa3.v[0], fmaf((float)h3.v[1], (float)xa3.v[1], a3));
            b0 = fmaf((float)h0.v[0], (float)xb0.v[0], fmaf((float)h0.v[1], (float)xb0.v[1], b0));
            b1 = fmaf((float)h1.v[0], (float)xb1.v[0], fmaf((float)h1.v[1], (float)xb1.v[1], b1));
            b2 = fmaf((float)h2.v[0], (float)xb2.v[0], fmaf((float)h2.v[1], (float)xb2.v[1], b2));
            b3 = fmaf((float)h3.v[0], (float)xb3.v[0], fmaf((float)h3.v[1], (float)xb3.v[1], b3));
#endif
        }
        float pre0 = xc0 + ((a0 + a1) + (a2 + a3));   // gate g0
        float pre1 = xc1 + ((b0 + b1) + (b2 + b3));   // gate g1
        float sA = __shfl_xor(pre0, 1);               // partner's g0
        float sB = __shfl_xor(pre1, 1);               // partner's g1
        float gi = gp ? sA : pre0;
        float gf = gp ? sB : pre1;
        float gg = gp ? pre0 : sA;
        float go = gp ? pre1 : sB;
        c = fsig(gf) * c + fsig(gi) * ftanh(gg);
        float hval = fsig(go) * ftanh(c);
        int nxt = cur ^ 1;
        if (gp == 0) {
            ((_Float16*)&hsm[nxt][0])[ch] = (_Float16)hval;
            hb[s * H + ch] = hval;
        }
        __syncthreads();
        cur = nxt;
    }
}

// ---------------------------------------------------------------------------
// k_amp_kprep (round-12 fusion): blocks 0-31 = amp, 32-287 = kprep.
// ---------------------------------------------------------------------------
__global__ __launch_bounds__(256) void k_amp_kprep(const float* __restrict__ hs,
                                                   const float* __restrict__ audio,
                                                   const float* __restrict__ video,
                                                   const float* __restrict__ pW, const float* __restrict__ pb,
                                                   const float* __restrict__ aW1, const float* __restrict__ ab1,
                                                   const float* __restrict__ aW2, const float* __restrict__ ab2,
                                                   const float* __restrict__ aW3, const float* __restrict__ ab3,
                                                   const float* __restrict__ vW1, const float* __restrict__ vb1,
                                                   const float* __restrict__ vW2, const float* __restrict__ vb2,
                                                   const float* __restrict__ vW3, const float* __restrict__ vb3,
                                                   float* __restrict__ ampT, float* __restrict__ ampA,
                                                   float* __restrict__ ampV,
                                                   const float* __restrict__ kr,
                                                   const float* __restrict__ ki,
                                                   unsigned short* __restrict__ Bh) {
    __shared__ float sPW[16 * 128], sA1[16 * 74], sV1[16 * 35];
    __shared__ float sA2[256], sA3[256], sV2[256], sV3[256];
    __shared__ float sbp[16], sba1[16], sba2[16], sba3[16], sbv1[16], sbv2[16], sbv3[16];
    __shared__ float red[256];
    int tid = threadIdx.x;

    if (blockIdx.x >= 32) {
        // ---- kprep: normalize K, build bf16 B (hi only) ----
        int u = blockIdx.x - 32;
        const float* r0 = kr + (size_t)u * Mdim;
        const float* i0 = ki + (size_t)u * Mdim;
        float ss = 0.f;
        for (int d = tid; d < Mdim; d += 256) {
            float a = r0[d], b2 = i0[d];
            ss = fmaf(a, a, fmaf(b2, b2, ss));
        }
        red[tid] = ss; __syncthreads();
        for (int off = 128; off > 0; off >>= 1) {
            if (tid < off) red[tid] += red[tid + off];
            __syncthreads();
        }
        float inv = 1.f / sqrtf(red[0]);
        for (int d = tid; d < Mdim; d += 256) {
            float xr = r0[d] * inv, xi = i0[d] * inv;
            unsigned short hr = f2bf(xr);
            unsigned short hi_ = f2bf(xi);
            int ch = d >> 5;
            int kl = (d & 31) * 2;
            size_t base = ((size_t)ch * 512 + 2 * u) * 64 + kl;     // row 2u
            Bh[base] = hr;  Bh[base + 1] = hi_;
            size_t base2 = base + 64;                                // row 2u+1
            Bh[base2] = hi_ ^ 0x8000; Bh[base2 + 1] = hr;
        }
        return;
    }

    // ---- amp ----
    for (int i = tid; i < 16 * 128; i += 256) sPW[i] = pW[i];
    for (int i = tid; i < 16 * 74; i += 256) sA1[i] = aW1[i];
    for (int i = tid; i < 16 * 35; i += 256) sV1[i] = vW1[i];
    if (tid < 256) { sA2[tid] = aW2[tid]; sA3[tid] = aW3[tid]; sV2[tid] = vW2[tid]; sV3[tid] = vW3[tid]; }
    if (tid < 16) {
        sbp[tid] = pb[tid];
        sba1[tid] = ab1[tid]; sba2[tid] = ab2[tid]; sba3[tid] = ab3[tid];
        sbv1[tid] = vb1[tid]; sbv2[tid] = vb2[tid]; sbv3[tid] = vb3[tid];
    }
    __syncthreads();
    int t = blockIdx.x * 256 + tid;

    const float* hrow = hs + (size_t)t * H;
    float accT[16];
#pragma unroll
    for (int m = 0; m < 16; m++) accT[m] = sbp[m];
    for (int k = 0; k < 128; k += 4) {
        float4 hv = *(const float4*)&hrow[k];
#pragma unroll
        for (int m = 0; m < 16; m++) {
            float4 wv = *(const float4*)&sPW[m * 128 + k];
            accT[m] = fmaf(hv.x, wv.x, fmaf(hv.y, wv.y, fmaf(hv.z, wv.z, fmaf(hv.w, wv.w, accT[m]))));
        }
    }
#pragma unroll
    for (int m = 0; m < 16; m++) ampT[t * 16 + m] = accT[m];

    float y1[16], y2[16];
    const float* arow = audio + (size_t)t * DA;
#pragma unroll 4
    for (int m = 0; m < 16; m++) {
        float a = sba1[m];
        for (int k = 0; k < DA; k++) a = fmaf(arow[k], sA1[m * DA + k], a);
        y1[m] = fmaxf(a, 0.f);
    }
#pragma unroll
    for (int m = 0; m < 16; m++) {
        float a = sba2[m];
#pragma unroll
        for (int k = 0; k < 16; k++) a = fmaf(y1[k], sA2[m * 16 + k], a);
        y2[m] = fmaxf(a, 0.f);
    }
#pragma unroll
    for (int m = 0; m < 16; m++) {
        float a = sba3[m];
#pragma unroll
        for (int k = 0; k < 16; k++) a = fmaf(y2[k], sA3[m * 16 + k], a);
        ampA[t * 16 + m] = fmaxf(a, 0.f);
    }
    const float* vrow = video + (size_t)t * DV;
#pragma unroll 4
    for (int m = 0; m < 16; m++) {
        float a = sbv1[m];
        for (int k = 0; k < DV; k++) a = fmaf(vrow[k], sV1[m * DV + k], a);
        y1[m] = fmaxf(a, 0.f);
    }
#pragma unroll
    for (int m = 0; m < 16; m++) {
        float a = sbv2[m];
#pragma unroll
        for (int k = 0; k < 16; k++) a = fmaf(y1[k], sV2[m * 16 + k], a);
        y2[m] = fmaxf(a, 0.f);
    }
#pragma unroll
    for (int m = 0; m < 16; m++) {
        float a = sbv3[m];
#pragma unroll
        for (int k = 0; k < 16; k++) a = fmaf(y2[k], sV3[m * 16 + k], a);
        ampV[t * 16 + m] = fmaxf(a, 0.f);
    }
}

// ---------------------------------------------------------------------------
// k_modality: per-b: norms, softmax over S, weight, z = a_n * e^{i phase}.
// ---------------------------------------------------------------------------
__global__ __launch_bounds__(128) void k_modality(const int* __restrict__ idx,
                                                  const float* __restrict__ pt,
                                                  const float* __restrict__ ampT,
                                                  const float* __restrict__ ampA,
                                                  const float* __restrict__ ampV,
                                                  const float* __restrict__ mweights,
                                                  float* __restrict__ zq, float* __restrict__ wt) {
    int b = blockIdx.x, s = threadIdx.x;
    __shared__ float red[128];
    int t = b * S + s;
    const float* amps0 = ampT + (size_t)t * 16;
    const float* amps1 = ampA + (size_t)t * 16;
    const float* amps2 = ampV + (size_t)t * 16;

    float m0 = mweights[0], m1 = mweights[1], m2 = mweights[2];
    float mx = fmaxf(m0, fmaxf(m1, m2));
    float e0 = expf(m0 - mx), e1 = expf(m1 - mx), e2 = expf(m2 - mx);
    float es = e0 + e1 + e2;
    float mw[3] = {e0 / es, e1 / es, e2 / es};

    int row = idx[t];
    float wacc = 0.f;
    for (int m = 0; m < 3; m++) {
        const float* amp = (m == 0) ? amps0 : (m == 1) ? amps1 : amps2;
        float av[16];
        float ss = 0.f;
#pragma unroll
        for (int c2 = 0; c2 < 16; c2++) { av[c2] = amp[c2]; ss = fmaf(av[c2], av[c2], ss); }
        float nrm = sqrtf(ss);
        red[s] = nrm; __syncthreads();
        for (int off = 64; off > 0; off >>= 1) {
            if (s < off) red[s] = fmaxf(red[s], red[s + off]);
            __syncthreads();
        }
        float rmax = red[0]; __syncthreads();
        float ex = expf(nrm - rmax);
        red[s] = ex; __syncthreads();
        for (int off = 64; off > 0; off >>= 1) {
            if (s < off) red[s] += red[s + off];
            __syncthreads();
        }
        float rsum = red[0]; __syncthreads();
        wacc = fmaf(mw[m], ex / rsum, wacc);

        float inv = 1.f / nrm;
        const float* ph = pt + ((size_t)m * V + row) * 16;
        float2* zdst = (float2*)zq + ((size_t)m * T_ + t) * 16;
#pragma unroll
        for (int c2 = 0; c2 < 16; c2++) {
            float an = av[c2] * inv;
            float p = ph[c2];
            zdst[c2] = make_float2(cosf(p) * an, sinf(p) * an);
        }
    }
    wt[t] = wacc;
}

// ---------------------------------------------------------------------------
// k_gmalpha v5 (round-17): Gm processes TWO K-sub-chunks per barrier pair
// (separate LDS buffers [2], identical per-sub-chunk code, same accumulation
// order -> bit-identical math). Barrier count halves: 256 -> 128. Alpha half
// = round-15 exact (stride 34). LDS union 55296 B; 2 blocks/CU (unchanged).
// ---------------------------------------------------------------------------
__global__ __launch_bounds__(256, 2) void k_gmalpha(const float* __restrict__ zq,
                                                    const unsigned short* __restrict__ Bh,
                                                    unsigned int* __restrict__ Gt32,
                                                    unsigned int* __restrict__ ahq,
                                                    unsigned int* __restrict__ alq) {
    __shared__ __align__(16) unsigned char smem[55296];
    int tid = threadIdx.x;

    if (blockIdx.x < 512) {
        // ================= Gm =================
        // Ah[sc]: 64x72 ushort at sc*9216 ; Bhs[sc]: 128x72 ushort at 18432+sc*18432
        int xcd = blockIdx.x & 7;
        int nt = xcd >> 1;                            // panel pinned per XCD pair
        int mt = ((blockIdx.x >> 3) << 1) | (xcd & 1);
        int t0 = mt * 64, n0 = nt * 128;

        int tl = tid >> 2, qf = tid & 3;
        int tok = t0 + tl;
        int h = qf >> 1;
        int d3b = (qf & 1) * 8;
        const float2* zq2 = (const float2*)zq;
        float z3r[8], z3i[8];
#pragma unroll
        for (int j = 0; j < 8; j++) {
            float2 v = zq2[((size_t)2 * T_ + tok) * 16 + d3b + j];
            z3r[j] = v.x; z3i[j] = v.y;
        }

        int wid = tid >> 6, lane = tid & 63;
        int wn = wid >> 1, wt2 = wid & 1;
        int lrow = lane & 15, lk = lane >> 4;

        f32x4 acc[4][2];
#pragma unroll
        for (int fm = 0; fm < 4; fm++)
#pragma unroll
            for (int fn = 0; fn < 2; fn++) acc[fm][fn] = (f32x4){0.f, 0.f, 0.f, 0.f};

        union S8 { short8v v; unsigned short u[8]; };

        for (int cp = 0; cp < NCH / 2; cp++) {
            uint4 bvh[2][4];
#pragma unroll
            for (int sc = 0; sc < 2; sc++) {
                int ch = 2 * cp + sc;
                const unsigned short* srcH = Bh + ((size_t)ch * 512 + n0) * 64;
#pragma unroll
                for (int l = 0; l < 4; l++) {
                    int i2 = tid + 256 * l;
                    bvh[sc][l] = *(const uint4*)(srcH + (size_t)i2 * 8);
                }
            }

#pragma unroll
            for (int sc = 0; sc < 2; sc++) {
                int ch = 2 * cp + sc;
                unsigned short (*Ah)[72] = (unsigned short (*)[72])(smem + sc * 9216);
                unsigned short (*Bhs)[72] = (unsigned short (*)[72])(smem + 18432 + sc * 18432);
                int d1 = ch >> 3;
                int d2 = ((ch & 7) << 1) + h;
                float2 z1 = zq2[(size_t)tok * 16 + d1];
                float2 z2 = zq2[((size_t)T_ + tok) * 16 + d2];
                float w1r = z1.x - z1.y, w1i = z1.x + z1.y;
                float wr_ = w1r * z2.x - w1i * z2.y;
                float wi_ = w1r * z2.y + w1i * z2.x;
                S8 h0, h1;
#pragma unroll
                for (int j = 0; j < 8; j++) {
                    float pr_ = wr_ * z3r[j] - wi_ * z3i[j];
                    float pi_ = wr_ * z3i[j] + wi_ * z3r[j];
                    unsigned short phr = f2bf(pr_);
                    unsigned short phi = f2bf(pi_);
                    if (j < 4) {
                        h0.u[2 * j] = phr;     h0.u[2 * j + 1] = phi;
                    } else {
                        h1.u[2 * (j - 4)] = phr; h1.u[2 * (j - 4) + 1] = phi;
                    }
                }
                int aoff = h * 32 + (qf & 1) * 16;
                *(short8v*)&Ah[tl][aoff] = h0.v;
                *(short8v*)&Ah[tl][aoff + 8] = h1.v;
#pragma unroll
                for (int l = 0; l < 4; l++) {
                    int i2 = tid + 256 * l;
                    *(uint4*)&Bhs[i2 >> 3][(i2 & 7) * 8] = bvh[sc][l];
                }
            }
            __syncthreads();

#pragma unroll
            for (int sc = 0; sc < 2; sc++) {
                unsigned short (*Ah)[72] = (unsigned short (*)[72])(smem + sc * 9216);
                unsigned short (*Bhs)[72] = (unsigned short (*)[72])(smem + 18432 + sc * 18432);
#pragma unroll
                for (int kk = 0; kk < 2; kk++) {
                    short8v kf[4], ahf[2];
#pragma unroll
                    for (int fm = 0; fm < 4; fm++) {
                        int nr = wn * 64 + fm * 16 + lrow;
                        int co = kk * 32 + lk * 8;
                        kf[fm] = *(const short8v*)&Bhs[nr][co];
                    }
#pragma unroll
                    for (int fn = 0; fn < 2; fn++) {
                        int ro = wt2 * 32 + fn * 16 + lrow;
                        int co = kk * 32 + lk * 8;
                        ahf[fn] = *(const short8v*)&Ah[ro][co];
                    }
#pragma unroll
                    for (int fm = 0; fm < 4; fm++)
#pragma unroll
                        for (int fn = 0; fn < 2; fn++)
                            acc[fm][fn] = __builtin_amdgcn_mfma_f32_16x16x32_bf16(kf[fm], ahf[fn], acc[fm][fn], 0, 0, 0);
                }
            }
            __syncthreads();
        }

#pragma unroll
        for (int fm = 0; fm < 4; fm++)
#pragma unroll
            for (int fn = 0; fn < 2; fn++) {
                int t = t0 + wt2 * 32 + fn * 16 + lrow;
                int bb = t >> 7, tl2 = t & 127;
#pragma unroll
                for (int p = 0; p < 2; p++) {
                    int ng = n0 + wn * 64 + fm * 16 + lk * 4 + 2 * p;
                    float vr = acc[fm][fn][2 * p];
                    float vi = acc[fm][fn][2 * p + 1];
                    unsigned int evenw = (unsigned int)f2bf(vr) | ((unsigned int)f2bf(-vi) << 16);
                    unsigned int oddw  = (unsigned int)f2bf(vi) | ((unsigned int)f2bf(vr) << 16);
                    Gt32[((size_t)bb * 512 + ng) * 128 + tl2] = evenw;
                    Gt32[((size_t)bb * 512 + ng + 1) * 128 + tl2] = oddw;
                }
            }
        return;
    }

    // ================= alpha (round-15 exact) =================
    float* zs = (float*)smem;     // 3*128*34 floats = 52224 B (fits in 55296)
    int bidx = blockIdx.x - 512;
    int b = bidx >> 3, s0 = (bidx & 7) * 16;
    int sl = tid >> 4, tg = tid & 15;

    for (int i = tid; i < 3 * 128 * 32; i += 256) {
        int m = i >> 12;
        int rem = i & 4095;
        int tok = rem >> 5, jj = rem & 31;
        zs[(m * 128 + tok) * 34 + jj] = zq[((size_t)m * T_ + b * S) * 32 + rem];
    }
    __syncthreads();

    int s = s0 + sl;
    float pr[8], pi[8];
#pragma unroll
    for (int j = 0; j < 8; j++) { pr[j] = 1.f; pi[j] = 0.f; }
    for (int m = 0; m < 3; m++) {
        float sr_[16], si_[16];
        const float* zss = &zs[(m * 128 + s) * 34];
#pragma unroll
        for (int c2 = 0; c2 < 16; c2++) { sr_[c2] = zss[2 * c2]; si_[c2] = zss[2 * c2 + 1]; }
#pragma unroll
        for (int j = 0; j < 8; j++) {
            int t = tg + 16 * j;
            const float* zst = &zs[(m * 128 + t) * 34];
            float dr = 0.f, di = 0.f;
#pragma unroll
            for (int c2 = 0; c2 < 16; c2++) {
                float br_ = zst[2 * c2], bi_ = zst[2 * c2 + 1];
                dr = fmaf(sr_[c2], br_, fmaf(-si_[c2], bi_, dr));
                di = fmaf(sr_[c2], bi_, fmaf(si_[c2], br_, di));
            }
            float nr = pr[j] * dr - pi[j] * di;
            float ni = pr[j] * di + pi[j] * dr;
            pr[j] = nr; pi[j] = ni;
        }
    }
    float ur[8], ui[8];
#pragma unroll
    for (int j = 0; j < 8; j++) { ur[j] = -2.f * pi[j]; ui[j] = 2.f * pr[j]; }

    float mr = ur[0], mi_ = ui[0];
#pragma unroll
    for (int j = 1; j < 8; j++) { mr = fmaxf(mr, ur[j]); mi_ = fmaxf(mi_, ui[j]); }
    for (int off = 1; off < 16; off <<= 1) {
        mr = fmaxf(mr, __shfl_xor(mr, off));
        mi_ = fmaxf(mi_, __shfl_xor(mi_, off));
    }
    float sr = 0.f, si = 0.f;
#pragma unroll
    for (int j = 0; j < 8; j++) {
        ur[j] = expf(ur[j] - mr); sr += ur[j];
        ui[j] = expf(ui[j] - mi_); si += ui[j];
    }
    for (int off = 1; off < 16; off <<= 1) {
        sr += __shfl_xor(sr, off);
        si += __shfl_xor(si, off);
    }
    float invr = 1.f / sr, invi = 1.f / si;
    unsigned int* ah_ = ahq + ((size_t)b * S + s) * 128;
    unsigned int* al_ = alq + ((size_t)b * S + s) * 128;
#pragma unroll
    for (int j = 0; j < 8; j++) {
        int t = tg + 16 * j;
        float arj = ur[j] * invr;
        float aij = ui[j] * invi;
        if (t == s) arj += 1.f;
        unsigned short rh = f2bf(arj), ih = f2bf(aij);
        unsigned short rl = f2bf(arj - bf2f(rh)), il = f2bf(aij - bf2f(ih));
        ah_[t] = (unsigned int)rh | ((unsigned int)ih << 16);
        al_[t] = (unsigned int)rl | ((unsigned int)il << 16);
    }
}

// ---------------------------------------------------------------------------
// k_meas_mfma: per-batch real GEMM in = A' @ Gt^T via MFMA; epilogue
// meas[b,u] = sum_s w[s]*(in[s,2u]^2 + in[s,2u+1]^2).
// ---------------------------------------------------------------------------
__global__ __launch_bounds__(256, 2) void k_meas_mfma(const unsigned short* __restrict__ Aq,
                                                      const unsigned short* __restrict__ Alq,
                                                      const unsigned short* __restrict__ Gt,
                                                      const float* __restrict__ wt,
                                                      float* __restrict__ meas) {
    int tid = threadIdx.x;
    int b = blockIdx.x >> 2, nq = blockIdx.x & 3;
    int wid = tid >> 6, lane = tid & 63;
    int ws = wid >> 1, wn2 = wid & 1;
    int lrow = lane & 15, lk = lane >> 4;

    f32x4 acc[4][4];
#pragma unroll
    for (int fm = 0; fm < 4; fm++)
#pragma unroll
        for (int fn = 0; fn < 4; fn++) acc[fm][fn] = (f32x4){0.f, 0.f, 0.f, 0.f};

    const unsigned short* Ab = Aq + (size_t)b * 128 * 256;
    const unsigned short* Alb = Alq + (size_t)b * 128 * 256;
    const unsigned short* Gb = Gt + (size_t)b * 512 * 256;

    for (int kc = 0; kc < 8; kc++) {
        int ko = kc * 32 + lk * 8;
        short8v ah[4], al[4], bt[4];
#pragma unroll
        for (int fm = 0; fm < 4; fm++) {
            int s = ws * 64 + fm * 16 + lrow;
            ah[fm] = *(const short8v*)(Ab + (size_t)s * 256 + ko);
            al[fm] = *(const short8v*)(Alb + (size_t)s * 256 + ko);
        }
#pragma unroll
        for (int fn = 0; fn < 4; fn++) {
            int n = nq * 128 + wn2 * 64 + fn * 16 + lrow;
            bt[fn] = *(const short8v*)(Gb + (size_t)n * 256 + ko);
        }
#pragma unroll
        for (int fm = 0; fm < 4; fm++)
#pragma unroll
            for (int fn = 0; fn < 4; fn++) {
                acc[fm][fn] = __builtin_amdgcn_mfma_f32_16x16x32_bf16(ah[fm], bt[fn], acc[fm][fn], 0, 0, 0);
                acc[fm][fn] = __builtin_amdgcn_mfma_f32_16x16x32_bf16(al[fm], bt[fn], acc[fm][fn], 0, 0, 0);
            }
    }

    __shared__ float red[4][4][16];
    float part[4] = {0.f, 0.f, 0.f, 0.f};
#pragma unroll
    for (int fm = 0; fm < 4; fm++)
#pragma unroll
        for (int j = 0; j < 4; j++) {
            int s = ws * 64 + fm * 16 + lk * 4 + j;
            float w = wt[b * S + s];
#pragma unroll
            for (int fn = 0; fn < 4; fn++) {
                float v = acc[fm][fn][j];
                part[fn] = fmaf(w * v, v, part[fn]);
            }
        }
#pragma unroll
    for (int fn = 0; fn < 4; fn++) {
        part[fn] += __shfl_xor(part[fn], 16);
        part[fn] += __shfl_xor(part[fn], 32);
    }
    if (lane < 16) {
#pragma unroll
        for (int fn = 0; fn < 4; fn++) red[wid][fn][lane] = part[fn];
    }
    __syncthreads();
    if (tid < 64) {
        int n0 = 2 * tid;
        int wn2a = n0 >> 6, rem = n0 & 63, fna = rem >> 4, ca = rem & 15;
        float v = red[wn2a][fna][ca] + red[2 + wn2a][fna][ca]
                + red[wn2a][fna][ca + 1] + red[2 + wn2a][fna][ca + 1];
        meas[(size_t)b * UNITS + nq * 64 + tid] = v;
    }
}

// ---------------------------------------------------------------------------
// k_head: 3-layer MLP head.
// ---------------------------------------------------------------------------
__global__ __launch_bounds__(64) void k_head(const float* __restrict__ meas,
                                             const float* __restrict__ fc1W, const float* __restrict__ fc1b,
                                             const float* __restrict__ fc2W, const float* __restrict__ fc2b,
                                             const float* __restrict__ fc3W, const float* __restrict__ fc3b,
                                             float* __restrict__ out) {
    int b = blockIdx.x, j = threadIdx.x;
    __shared__ float y[64];
    float a = fc1b[j];
    for (int u = 0; u < 256; u++) a = fmaf(meas[(size_t)b * 256 + u], fc1W[j * 256 + u], a);
    y[j] = fmaxf(a, 0.f);
    __syncthreads();
    float a2 = fc2b[j];
#pragma unroll
    for (int k = 0; k < 64; k++) a2 = fmaf(y[k], fc2W[j * 64 + k], a2);
    a2 = fmaxf(a2, 0.f);
    float v = a2 * fc3W[j];
    for (int off = 32; off > 0; off >>= 1) v += __shfl_down(v, off);
    if (j == 0) out[b] = v + fc3b[0];
}

// ---------------------------------------------------------------------------
extern "C" void kernel_launch(void* const* d_in, const int* in_sizes, int n_in,
                              void* d_out, int out_size, void* d_ws, size_t ws_size,
                              hipStream_t stream) {
    const int* text_idx = (const int*)d_in[0];
    const float* audio = (const float*)d_in[1];
    const float* video = (const float*)d_in[2];
    const float* emb = (const float*)d_in[3];
    const float* pt = (const float*)d_in[4];
    const float* Wih = (const float*)d_in[5];
    const float* Whh = (const float*)d_in[6];
    const float* bih = (const float*)d_in[7];
    const float* bhh = (const float*)d_in[8];
    const float* pW = (const float*)d_in[9];
    const float* pb = (const float*)d_in[10];
    const float* aW1 = (const float*)d_in[11];
    const float* ab1 = (const float*)d_in[12];
    const float* aW2 = (const float*)d_in[13];
    const float* ab2 = (const float*)d_in[14];
    const float* aW3 = (const float*)d_in[15];
    const float* ab3 = (const float*)d_in[16];
    const float* vW1 = (const float*)d_in[17];
    const float* vb1 = (const float*)d_in[18];
    const float* vW2 = (const float*)d_in[19];
    const float* vb2 = (const float*)d_in[20];
    const float* vW3 = (const float*)d_in[21];
    const float* vb3 = (const float*)d_in[22];
    const float* mweights = (const float*)d_in[23];
    const float* mkr = (const float*)d_in[24];
    const float* mki = (const float*)d_in[25];
    const float* fc1W = (const float*)d_in[26];
    const float* fc1b = (const float*)d_in[27];
    const float* fc2W = (const float*)d_in[28];
    const float* fc2b = (const float*)d_in[29];
    const float* fc3W = (const float*)d_in[30];
    const float* fc3b = (const float*)d_in[31];

    float* ws = (float*)d_ws;
    size_t off = 0;
    float* hs = ws + off;   off += (size_t)T_ * H;          // 4 MB
    float* xW = ws + off;   off += (size_t)T_ * 512;        // 16 MB; reused as Gt
    float* ampT = ws + off; off += (size_t)T_ * 16;
    float* ampA = ws + off; off += (size_t)T_ * 16;
    float* ampV = ws + off; off += (size_t)T_ * 16;
    float* zq = ws + off;   off += (size_t)3 * T_ * 32;     // 3 MB
    float* wt = ws + off;   off += (size_t)T_;
    unsigned short* BhW = (unsigned short*)(ws + off); off += (size_t)2097152;  // 8 MB
    unsigned int* ahq = (unsigned int*)(ws + off); off += (size_t)1048576;      // 4 MB
    unsigned int* alq = (unsigned int*)(ws + off); off += (size_t)1048576;      // 4 MB
    float* meas = ws + off; off += (size_t)B * UNITS;
    (void)ws_size; (void)in_sizes; (void)n_in; (void)out_size;

    k_embed<<<256, 256, 0, stream>>>(text_idx, emb, Wih, bih, bhh, xW);
    k_lstm<<<B, 256, 0, stream>>>(xW, Whh, hs);
    k_amp_kprep<<<288, 256, 0, stream>>>(hs, audio, video, pW, pb,
                                         aW1, ab1, aW2, ab2, aW3, ab3,
                                         vW1, vb1, vW2, vb2, vW3, vb3,
                                         ampT, ampA, ampV,
                                         mkr, mki, BhW);
    k_modality<<<B, 128, 0, stream>>>(text_idx, pt, ampT, ampA, ampV, mweights, zq, wt);
    k_gmalpha<<<1024, 256, 0, stream>>>(zq, BhW, (unsigned int*)xW /* = Gt */, ahq, alq);
    k_meas_mfma<<<256, 256, 0, stream>>>((const unsigned short*)ahq,
                                         (const unsigned short*)alq,
                                         (const unsigned short*)xW /* Gt */,
                                         wt, meas);
    k_head<<<B, 64, 0, stream>>>(meas, fc1W, fc1b, fc2W, fc2b, fc3W, fc3b, (float*)d_out);
}